// Round 3
// baseline (1806.625 us; speedup 1.0000x reference)
//
#include <hip/hip_runtime.h>

// Problem constants
constexpr int N_TOK = 8192;      // B*S
constexpr int D_IN  = 2048;
constexpr int H_OUT = 4096;
constexpr int NEXP  = 8;
constexpr float ENT_W = 0.1f;
constexpr float MAX_USAGE = 0.3f;

// GEMM tiling: 256x256 tile, BK=64, 8 waves (2M x 4N), 8-phase schedule
constexpr int BM = 256;
constexpr int BN = 256;
constexpr int BKK = 64;
constexpr int NKT = D_IN / BKK;        // 32 K-tiles
constexpr int TILES_H2 = H_OUT / BN;   // 16
constexpr int TILES_M2 = N_TOK / BM;   // 32 worst-case token tiles / expert
constexpr int REGION = 8192;           // per-expert list capacity

typedef __attribute__((ext_vector_type(8))) short bf16x8;
typedef __attribute__((ext_vector_type(4))) float f32x4;

__device__ __forceinline__ short f2bf(float f) {
    unsigned u = __float_as_uint(f);
    u += 0x7FFF + ((u >> 16) & 1);   // RNE
    return (short)(u >> 16);
}

__device__ __forceinline__ void gload16(const void* g, void* l) {
    __builtin_amdgcn_global_load_lds(
        (const __attribute__((address_space(1))) unsigned int*)g,
        (__attribute__((address_space(3))) unsigned int*)l, 16, 0, 0);
}

// ---------------------------------------------------------------------------
// fp32 -> bf16 bulk convert (used for expert_w only; x is fused into gate)
// ---------------------------------------------------------------------------
__global__ __launch_bounds__(256) void cvt_kernel(
    const float* __restrict__ in, short* __restrict__ out, int n8)
{
    int stride = gridDim.x * 256;
    for (int i = blockIdx.x * 256 + threadIdx.x; i < n8; i += stride) {
        const float4* p = (const float4*)in + (size_t)i * 2;
        float4 a = p[0], b = p[1];
        bf16x8 v;
        v[0] = f2bf(a.x); v[1] = f2bf(a.y); v[2] = f2bf(a.z); v[3] = f2bf(a.w);
        v[4] = f2bf(b.x); v[5] = f2bf(b.y); v[6] = f2bf(b.z); v[7] = f2bf(b.w);
        *(bf16x8*)(out + (size_t)i * 8) = v;
    }
}

// ---------------------------------------------------------------------------
// Kernel 1: gating. One wave per token. Also converts the token's x row to
// bf16 (fuses the former cvt_x pass). No global atomics (counts moved to
// scatter). Entropy partial per block (deterministic).
// ---------------------------------------------------------------------------
__global__ __launch_bounds__(256) void gate_kernel(
    const float* __restrict__ x, const float* __restrict__ gate_w,
    const float* __restrict__ gate_b, int* __restrict__ topk_idx,
    float* __restrict__ topk_w, float* __restrict__ ent_partial,
    short* __restrict__ xb)
{
    __shared__ float ent_s[4];
    const int wv = threadIdx.x >> 6;
    const int lane = threadIdx.x & 63;
    const int t = blockIdx.x * 4 + wv;

    float acc[NEXP];
#pragma unroll
    for (int e = 0; e < NEXP; ++e) acc[e] = 0.f;

    const float4* xr = (const float4*)(x + (size_t)t * D_IN);
    short* xbr = xb + (size_t)t * D_IN;
#pragma unroll
    for (int i = 0; i < D_IN / 256; ++i) {           // 8 iters
        float4 xv = xr[lane + i * 64];
        short4 s4;
        s4.x = f2bf(xv.x); s4.y = f2bf(xv.y); s4.z = f2bf(xv.z); s4.w = f2bf(xv.w);
        *(short4*)(xbr + i * 256 + lane * 4) = s4;
#pragma unroll
        for (int e = 0; e < NEXP; ++e) {
            float4 gv = ((const float4*)(gate_w + e * D_IN))[lane + i * 64];
            acc[e] += xv.x * gv.x + xv.y * gv.y + xv.z * gv.z + xv.w * gv.w;
        }
    }
#pragma unroll
    for (int e = 0; e < NEXP; ++e)
#pragma unroll
        for (int m = 32; m >= 1; m >>= 1) acc[e] += __shfl_xor(acc[e], m, 64);

    if (lane == 0) {
        float lg[NEXP], p[NEXP];
        float mx = -1e30f;
#pragma unroll
        for (int e = 0; e < NEXP; ++e) { lg[e] = acc[e] + gate_b[e]; mx = fmaxf(mx, lg[e]); }
        float s = 0.f;
#pragma unroll
        for (int e = 0; e < NEXP; ++e) { p[e] = expf(lg[e] - mx); s += p[e]; }
        float inv = 1.f / s;
        float ent = 0.f;
#pragma unroll
        for (int e = 0; e < NEXP; ++e) { p[e] *= inv; ent -= p[e] * logf(p[e] + 1e-10f); }
        int e1 = 0; float b1 = p[0];
#pragma unroll
        for (int e = 1; e < NEXP; ++e) if (p[e] > b1) { b1 = p[e]; e1 = e; }
        int e2 = (e1 == 0) ? 1 : 0; float b2 = p[e2];
#pragma unroll
        for (int e = 0; e < NEXP; ++e)
            if (e != e1 && e != ((e1 == 0) ? 1 : 0) && p[e] > b2) { b2 = p[e]; e2 = e; }
        topk_idx[2 * t]     = e1;  topk_idx[2 * t + 1] = e2;
        topk_w[2 * t]       = b1;  topk_w[2 * t + 1]   = b2;
        ent_s[wv] = ent;
    }
    __syncthreads();
    if (threadIdx.x == 0)
        ent_partial[blockIdx.x] = ent_s[0] + ent_s[1] + ent_s[2] + ent_s[3];
}

// ---------------------------------------------------------------------------
// Kernel 2: scatter. LDS-binned: 1 global atomic per (block, expert) instead
// of 2 per token. Writes into fixed per-expert regions (e*REGION + pos).
// Row order within a region is race-dependent; the GEMM output is invariant.
// ---------------------------------------------------------------------------
__global__ __launch_bounds__(256) void scatter_kernel(
    const int* __restrict__ topk_idx, const float* __restrict__ topk_w,
    int* __restrict__ cursors, int* __restrict__ tok_list,
    float* __restrict__ w_list)
{
    __shared__ int lcnt[NEXP], lbase[NEXP];
    const int tid = threadIdx.x;
    const int t = blockIdx.x * 256 + tid;
    if (tid < NEXP) lcnt[tid] = 0;
    __syncthreads();
    int e0 = topk_idx[2 * t], e1 = topk_idx[2 * t + 1];
    float w0 = topk_w[2 * t], w1 = topk_w[2 * t + 1];
    int p0 = atomicAdd(&lcnt[e0], 1);
    int p1 = atomicAdd(&lcnt[e1], 1);
    __syncthreads();
    if (tid < NEXP) lbase[tid] = atomicAdd(&cursors[tid], lcnt[tid]);
    __syncthreads();
    int d0 = e0 * REGION + lbase[e0] + p0;
    int d1 = e1 * REGION + lbase[e1] + p1;
    tok_list[d0] = t;  w_list[d0] = w0;
    tok_list[d1] = t;  w_list[d1] = w1;
}

// ---------------------------------------------------------------------------
// Kernel 3: finalize — entropy reduce + overuse penalty from counts(=cursors).
// ---------------------------------------------------------------------------
__global__ __launch_bounds__(256) void finalize_kernel(
    const int* __restrict__ counts, const float* __restrict__ ent_partial,
    float* __restrict__ loss_out)
{
    __shared__ float red[256];
    float s = 0.f;
    for (int i = threadIdx.x; i < N_TOK / 4; i += 256) s += ent_partial[i];
    red[threadIdx.x] = s;
    __syncthreads();
    for (int st = 128; st > 0; st >>= 1) {
        if (threadIdx.x < st) red[threadIdx.x] += red[threadIdx.x + st];
        __syncthreads();
    }
    if (threadIdx.x == 0) {
        float loss = ENT_W * red[0] / (float)N_TOK;
        for (int e = 0; e < NEXP; ++e) {
            float r = (float)counts[e] / (float)N_TOK - MAX_USAGE;
            if (r > 0.f) loss += r;
        }
        loss_out[0] = loss;
    }
}

// ---------------------------------------------------------------------------
// Kernel 4: grouped GEMM, 256x256 8-phase structure (T2+T3+T4+T5).
// 8 waves (2M x 4N), per-wave 128x64 output = acc[8][4] of 16x16 frags.
// LDS: double-buffered A/B [2][256][64] bf16 = 128 KB. Staging via
// global_load_lds w=16, linear LDS dest + involution-swizzled global source;
// frag ds_read applies the same involution (0 conflicts, verified r2).
// Per K-tile: 4 phases {ds_read subtile + stage -> raw barrier -> setprio ->
// 16 MFMA -> barrier}; vmcnt(0) only at the K-tile boundary (prefetch loads
// span the 4 phases -> staging latency hidden under MFMA).
// ---------------------------------------------------------------------------
__global__ __launch_bounds__(512, 2) void moe_gemm(
    const short* __restrict__ xb, const short* __restrict__ wb,
    const float* __restrict__ expert_b, const int* __restrict__ tok_list,
    const float* __restrict__ w_list, const int* __restrict__ counts,
    float* __restrict__ out)
{
    const int bid = blockIdx.x;
    const int e   = bid >> 9;              // / (16*32)
    const int rem = bid & 511;
    const int th  = rem >> 5;              // H-tile (B panel reuse: tm inner)
    const int tm  = rem & 31;

    const int cnt = counts[e];
    if (tm * BM >= cnt) return;
    const int valid = cnt - tm * BM;
    const int hbase = th * BN;

    __shared__ __align__(16) short A_s[2][BM * BKK];   // 2 x 32 KB
    __shared__ __align__(16) short B_s[2][BM * BKK];   // 2 x 32 KB
    __shared__ int   tok_s[BM];
    __shared__ float wgt_s[BM];

    const int tid = threadIdx.x;
    if (tid < BM) {
        bool v = tid < valid;
        int src = e * REGION + tm * BM + tid;
        tok_s[tid] = v ? tok_list[src] : 0;
        wgt_s[tid] = v ? w_list[src] : 0.f;
    }
    __syncthreads();

    const int lane = tid & 63, wv = tid >> 6;
    const int wm = wv >> 2, wn = wv & 3;
    const int rr = lane & 15, kg = lane >> 4;

    // ---- staging: 2048 16B-chunks per tile (A and B each); thread owns
    // chunks tid + j*512, j=0..3. chunk c: row=c>>3, slot=c&7; source slot
    // is swizzled s^=(row&7), LDS dest stays linear (rule 21 both-sides).
    const char* a_src[4];
    const char* b_src[4];
    int dst_off[4];                          // shorts; wave-uniform (+lane*16B by HW)
#pragma unroll
    for (int j = 0; j < 4; ++j) {
        int c = tid + j * 512, row = c >> 3, s2 = (c & 7) ^ (row & 7);
        a_src[j] = (const char*)(xb + (size_t)tok_s[row] * D_IN) + s2 * 16;
        b_src[j] = (const char*)(wb + ((size_t)e * H_OUT + hbase + row) * D_IN) + s2 * 16;
        dst_off[j] = (j * 512 + wv * 64) * 8;
    }

    // ---- fragment read bases: row&7 == rr&7 for all frags of this thread,
    // so the swizzled k-slot is thread-constant; frag addr = base + mi*2048.
    const int sA0 = ((kg) ^ (rr & 7)) * 16;        // bytes, k2=0
    const int sA1 = ((4 + kg) ^ (rr & 7)) * 16;    // bytes, k2=1
    const int Abase = (wm * 128 + rr) * 128;       // bytes
    const int Bbase = (wn * 64 + rr) * 128;        // bytes

    f32x4 acc[8][4] = {};

    // ---- prologue: stage K-tile 0 into buf 0, full drain once.
#pragma unroll
    for (int j = 0; j < 4; ++j) {
        gload16(a_src[j], (short*)A_s[0] + dst_off[j]); a_src[j] += 128;
        gload16(b_src[j], (short*)B_s[0] + dst_off[j]); b_src[j] += 128;
    }
    asm volatile("s_waitcnt vmcnt(0)" ::: "memory");
    __builtin_amdgcn_sched_barrier(0);
    __syncthreads();

#define STAGE_A(j) { gload16(a_src[j], An + dst_off[j]); a_src[j] += 128; }
#define STAGE_B(j) { gload16(b_src[j], Bn + dst_off[j]); b_src[j] += 128; }

    for (int kt = 0; kt < NKT; ++kt) {
        const char* Ac = (const char*)A_s[kt & 1];
        const char* Bc = (const char*)B_s[kt & 1];
        short* An = (short*)A_s[(kt + 1) & 1];
        short* Bn = (short*)B_s[(kt + 1) & 1];
        const bool pre = (kt + 1 < NKT);

        bf16x8 af[4][2], bf_[4][2];

        // ---- PH0: read A m0-3 (both k2) + B n0-3 (k2=0); stage A0,B0,A1
#pragma unroll
        for (int mi = 0; mi < 4; ++mi) {
            af[mi][0] = *(const bf16x8*)(Ac + Abase + mi * 2048 + sA0);
            af[mi][1] = *(const bf16x8*)(Ac + Abase + mi * 2048 + sA1);
        }
#pragma unroll
        for (int ni = 0; ni < 4; ++ni)
            bf_[ni][0] = *(const bf16x8*)(Bc + Bbase + ni * 2048 + sA0);
        if (pre) { STAGE_A(0); STAGE_B(0); STAGE_A(1); }
        __builtin_amdgcn_s_barrier();
        __builtin_amdgcn_s_setprio(1);
#pragma unroll
        for (int mi = 0; mi < 4; ++mi)
#pragma unroll
            for (int ni = 0; ni < 4; ++ni)
                acc[mi][ni] = __builtin_amdgcn_mfma_f32_16x16x32_bf16(
                    af[mi][0], bf_[ni][0], acc[mi][ni], 0, 0, 0);
        __builtin_amdgcn_s_setprio(0);
        __builtin_amdgcn_s_barrier();

        // ---- PH1: read B n0-3 (k2=1); stage B1,A2,B2
#pragma unroll
        for (int ni = 0; ni < 4; ++ni)
            bf_[ni][1] = *(const bf16x8*)(Bc + Bbase + ni * 2048 + sA1);
        if (pre) { STAGE_B(1); STAGE_A(2); STAGE_B(2); }
        __builtin_amdgcn_s_barrier();
        __builtin_amdgcn_s_setprio(1);
#pragma unroll
        for (int mi = 0; mi < 4; ++mi)
#pragma unroll
            for (int ni = 0; ni < 4; ++ni)
                acc[mi][ni] = __builtin_amdgcn_mfma_f32_16x16x32_bf16(
                    af[mi][1], bf_[ni][1], acc[mi][ni], 0, 0, 0);
        __builtin_amdgcn_s_setprio(0);
        __builtin_amdgcn_s_barrier();

        // ---- PH2: read A m4-7 (both k2, reuse regs); stage A3,B3
#pragma unroll
        for (int mi = 0; mi < 4; ++mi) {
            af[mi][0] = *(const bf16x8*)(Ac + Abase + (mi + 4) * 2048 + sA0);
            af[mi][1] = *(const bf16x8*)(Ac + Abase + (mi + 4) * 2048 + sA1);
        }
        if (pre) { STAGE_A(3); STAGE_B(3); }
        __builtin_amdgcn_s_barrier();
        __builtin_amdgcn_s_setprio(1);
#pragma unroll
        for (int mi = 0; mi < 4; ++mi)
#pragma unroll
            for (int ni = 0; ni < 4; ++ni)
                acc[mi + 4][ni] = __builtin_amdgcn_mfma_f32_16x16x32_bf16(
                    af[mi][0], bf_[ni][0], acc[mi + 4][ni], 0, 0, 0);
        __builtin_amdgcn_s_setprio(0);
        __builtin_amdgcn_s_barrier();

        // ---- PH3: no reads/stages; MFMA m4-7 k2=1; boundary vmcnt
        __builtin_amdgcn_s_setprio(1);
#pragma unroll
        for (int mi = 0; mi < 4; ++mi)
#pragma unroll
            for (int ni = 0; ni < 4; ++ni)
                acc[mi + 4][ni] = __builtin_amdgcn_mfma_f32_16x16x32_bf16(
                    af[mi][1], bf_[ni][1], acc[mi + 4][ni], 0, 0, 0);
        __builtin_amdgcn_s_setprio(0);
        if (pre) {
            asm volatile("s_waitcnt vmcnt(0)" ::: "memory");
            __builtin_amdgcn_sched_barrier(0);
        }
        __builtin_amdgcn_s_barrier();
    }
#undef STAGE_A
#undef STAGE_B

    // ---- epilogue: C/D layout col(H)=rr, row(token)=kg*4+i per frag.
    const float* bias = expert_b + (size_t)e * H_OUT + hbase;
#pragma unroll
    for (int mi = 0; mi < 8; ++mi) {
        int rb = wm * 128 + mi * 16 + kg * 4;
#pragma unroll
        for (int ni = 0; ni < 4; ++ni) {
            int col = wn * 64 + ni * 16 + rr;
            float be = bias[col];
#pragma unroll
            for (int i = 0; i < 4; ++i) {
                int r = rb + i;
                if (r < valid) {
                    float val = wgt_s[r] * (acc[mi][ni][i] + be);
                    atomicAdd(&out[(size_t)tok_s[r] * H_OUT + hbase + col], val);
                }
            }
        }
    }
}

// ---------------------------------------------------------------------------
// Workspace layout (<= 162 MB, same footprint as round 2):
//   0        topk_idx    64 KB
//   64K      topk_w      64 KB
//   128K     cursors     64 B
//   128K+256 ent_partial 8 KB
//   160K     tok_list    256 KB  (8 regions x 8192)
//   416K     w_list      256 KB
//   1M       xb  bf16    32 MB
//   34M      wb  bf16    128 MB
// ---------------------------------------------------------------------------
extern "C" void kernel_launch(void* const* d_in, const int* in_sizes, int n_in,
                              void* d_out, int out_size, void* d_ws, size_t ws_size,
                              hipStream_t stream) {
    const float* x        = (const float*)d_in[0];
    const float* gate_w   = (const float*)d_in[1];
    const float* gate_b   = (const float*)d_in[2];
    const float* expert_w = (const float*)d_in[3];
    const float* expert_b = (const float*)d_in[4];
    float* out = (float*)d_out;
    char* ws = (char*)d_ws;

    int*   topk_idx    = (int*)(ws);
    float* topk_w      = (float*)(ws + (64 << 10));
    int*   cursors     = (int*)(ws + (128 << 10));
    float* ent_partial = (float*)(ws + (128 << 10) + 256);
    int*   tok_list    = (int*)(ws + (160 << 10));
    float* w_list      = (float*)(ws + (416 << 10));
    short* xb          = (short*)(ws + (1ull << 20));
    short* wb          = (short*)(ws + (34ull << 20));

    hipMemsetAsync(cursors, 0, 64, stream);
    hipMemsetAsync(d_out, 0, (size_t)out_size * sizeof(float), stream);

    gate_kernel<<<N_TOK / 4, 256, 0, stream>>>(x, gate_w, gate_b, topk_idx,
                                               topk_w, ent_partial, xb);
    cvt_kernel<<<4096, 256, 0, stream>>>(expert_w, wb, (NEXP * H_OUT * D_IN) / 8);
    scatter_kernel<<<N_TOK / 256, 256, 0, stream>>>(topk_idx, topk_w, cursors,
                                                    tok_list, w_list);
    finalize_kernel<<<1, 256, 0, stream>>>(cursors, ent_partial,
                                           out + (size_t)N_TOK * H_OUT);
    moe_gemm<<<NEXP * TILES_H2 * TILES_M2, 512, 0, stream>>>(
        xb, wb, expert_b, tok_list, w_list, cursors, out);
}

// Round 4
// 825.981 us; speedup vs baseline: 2.1872x; 2.1872x over previous
//
#include <hip/hip_runtime.h>

// Problem constants
constexpr int N_TOK = 8192;      // B*S
constexpr int D_IN  = 2048;
constexpr int H_OUT = 4096;
constexpr int NEXP  = 8;
constexpr float ENT_W = 0.1f;
constexpr float MAX_USAGE = 0.3f;

// GEMM tiling (round-2 proven structure + explicit double-buffer)
constexpr int TM = 128;               // token-tile
constexpr int TH = 128;               // H-tile
constexpr int BK = 64;                // K-step (128 bytes bf16 per row)
constexpr int NKT = D_IN / BK;        // 32 K-tiles
constexpr int TILES_H = H_OUT / TH;   // 32
constexpr int TM_MAX  = N_TOK / TM;   // 64 worst-case token tiles per expert
constexpr int REGION  = 8192;         // per-expert list capacity
constexpr int BUFSZ   = TM * BK;      // shorts per LDS buffer (8192)

typedef __attribute__((ext_vector_type(8))) short bf16x8;
typedef __attribute__((ext_vector_type(4))) float f32x4;

__device__ __forceinline__ short f2bf(float f) {
    unsigned u = __float_as_uint(f);
    u += 0x7FFF + ((u >> 16) & 1);   // RNE
    return (short)(u >> 16);
}

__device__ __forceinline__ void gload16(const void* g, void* l) {
    __builtin_amdgcn_global_load_lds(
        (const __attribute__((address_space(1))) unsigned int*)g,
        (__attribute__((address_space(3))) unsigned int*)l, 16, 0, 0);
}

// ---------------------------------------------------------------------------
// fp32 -> bf16 bulk convert (expert_w only; x is fused into gate)
// ---------------------------------------------------------------------------
__global__ __launch_bounds__(256) void cvt_kernel(
    const float* __restrict__ in, short* __restrict__ out, int n8)
{
    int stride = gridDim.x * 256;
    for (int i = blockIdx.x * 256 + threadIdx.x; i < n8; i += stride) {
        const float4* p = (const float4*)in + (size_t)i * 2;
        float4 a = p[0], b = p[1];
        bf16x8 v;
        v[0] = f2bf(a.x); v[1] = f2bf(a.y); v[2] = f2bf(a.z); v[3] = f2bf(a.w);
        v[4] = f2bf(b.x); v[5] = f2bf(b.y); v[6] = f2bf(b.z); v[7] = f2bf(b.w);
        *(bf16x8*)(out + (size_t)i * 8) = v;
    }
}

// ---------------------------------------------------------------------------
// Kernel 1: gating. One wave per token; fuses x -> bf16 conversion.
// ---------------------------------------------------------------------------
__global__ __launch_bounds__(256) void gate_kernel(
    const float* __restrict__ x, const float* __restrict__ gate_w,
    const float* __restrict__ gate_b, int* __restrict__ topk_idx,
    float* __restrict__ topk_w, float* __restrict__ ent_partial,
    short* __restrict__ xb)
{
    __shared__ float ent_s[4];
    const int wv = threadIdx.x >> 6;
    const int lane = threadIdx.x & 63;
    const int t = blockIdx.x * 4 + wv;

    float acc[NEXP];
#pragma unroll
    for (int e = 0; e < NEXP; ++e) acc[e] = 0.f;

    const float4* xr = (const float4*)(x + (size_t)t * D_IN);
    short* xbr = xb + (size_t)t * D_IN;
#pragma unroll
    for (int i = 0; i < D_IN / 256; ++i) {           // 8 iters
        float4 xv = xr[lane + i * 64];
        short4 s4;
        s4.x = f2bf(xv.x); s4.y = f2bf(xv.y); s4.z = f2bf(xv.z); s4.w = f2bf(xv.w);
        *(short4*)(xbr + i * 256 + lane * 4) = s4;
#pragma unroll
        for (int e = 0; e < NEXP; ++e) {
            float4 gv = ((const float4*)(gate_w + e * D_IN))[lane + i * 64];
            acc[e] += xv.x * gv.x + xv.y * gv.y + xv.z * gv.z + xv.w * gv.w;
        }
    }
#pragma unroll
    for (int e = 0; e < NEXP; ++e)
#pragma unroll
        for (int m = 32; m >= 1; m >>= 1) acc[e] += __shfl_xor(acc[e], m, 64);

    if (lane == 0) {
        float lg[NEXP], p[NEXP];
        float mx = -1e30f;
#pragma unroll
        for (int e = 0; e < NEXP; ++e) { lg[e] = acc[e] + gate_b[e]; mx = fmaxf(mx, lg[e]); }
        float s = 0.f;
#pragma unroll
        for (int e = 0; e < NEXP; ++e) { p[e] = expf(lg[e] - mx); s += p[e]; }
        float inv = 1.f / s;
        float ent = 0.f;
#pragma unroll
        for (int e = 0; e < NEXP; ++e) { p[e] *= inv; ent -= p[e] * logf(p[e] + 1e-10f); }
        int e1 = 0; float b1 = p[0];
#pragma unroll
        for (int e = 1; e < NEXP; ++e) if (p[e] > b1) { b1 = p[e]; e1 = e; }
        int e2 = (e1 == 0) ? 1 : 0; float b2 = p[e2];
#pragma unroll
        for (int e = 0; e < NEXP; ++e)
            if (e != e1 && e != ((e1 == 0) ? 1 : 0) && p[e] > b2) { b2 = p[e]; e2 = e; }
        topk_idx[2 * t]     = e1;  topk_idx[2 * t + 1] = e2;
        topk_w[2 * t]       = b1;  topk_w[2 * t + 1]   = b2;
        ent_s[wv] = ent;
    }
    __syncthreads();
    if (threadIdx.x == 0)
        ent_partial[blockIdx.x] = ent_s[0] + ent_s[1] + ent_s[2] + ent_s[3];
}

// ---------------------------------------------------------------------------
// Kernel 2: scatter. LDS-binned, fixed per-expert regions.
// ---------------------------------------------------------------------------
__global__ __launch_bounds__(256) void scatter_kernel(
    const int* __restrict__ topk_idx, const float* __restrict__ topk_w,
    int* __restrict__ cursors, int* __restrict__ tok_list,
    float* __restrict__ w_list)
{
    __shared__ int lcnt[NEXP], lbase[NEXP];
    const int tid = threadIdx.x;
    const int t = blockIdx.x * 256 + tid;
    if (tid < NEXP) lcnt[tid] = 0;
    __syncthreads();
    int e0 = topk_idx[2 * t], e1 = topk_idx[2 * t + 1];
    float w0 = topk_w[2 * t], w1 = topk_w[2 * t + 1];
    int p0 = atomicAdd(&lcnt[e0], 1);
    int p1 = atomicAdd(&lcnt[e1], 1);
    __syncthreads();
    if (tid < NEXP) lbase[tid] = atomicAdd(&cursors[tid], lcnt[tid]);
    __syncthreads();
    int d0 = e0 * REGION + lbase[e0] + p0;
    int d1 = e1 * REGION + lbase[e1] + p1;
    tok_list[d0] = t;  w_list[d0] = w0;
    tok_list[d1] = t;  w_list[d1] = w1;
}

// ---------------------------------------------------------------------------
// Kernel 3: finalize — entropy reduce + overuse penalty (counts = cursors).
// ---------------------------------------------------------------------------
__global__ __launch_bounds__(256) void finalize_kernel(
    const int* __restrict__ counts, const float* __restrict__ ent_partial,
    float* __restrict__ loss_out)
{
    __shared__ float red[256];
    float s = 0.f;
    for (int i = threadIdx.x; i < N_TOK / 4; i += 256) s += ent_partial[i];
    red[threadIdx.x] = s;
    __syncthreads();
    for (int st = 128; st > 0; st >>= 1) {
        if (threadIdx.x < st) red[threadIdx.x] += red[threadIdx.x + st];
        __syncthreads();
    }
    if (threadIdx.x == 0) {
        float loss = ENT_W * red[0] / (float)N_TOK;
        for (int e = 0; e < NEXP; ++e) {
            float r = (float)counts[e] / (float)N_TOK - MAX_USAGE;
            if (r > 0.f) loss += r;
        }
        loss_out[0] = loss;
    }
}

// ---------------------------------------------------------------------------
// Kernel 4: grouped GEMM — round-2 128x128/BK=64/4-wave structure + explicit
// LDS double-buffer (T3-minimum): STAGE(next) at tile top, compute current,
// ONE barrier per K-tile at the end (its vmcnt drain has full-tile cover).
// Staging = global_load_lds w16, linear LDS dest, involution-swizzled global
// source; frag ds_read applies same involution (0 conflicts, verified r2).
// ---------------------------------------------------------------------------
__global__ __launch_bounds__(256) void moe_gemm(
    const short* __restrict__ xb, const short* __restrict__ wb,
    const float* __restrict__ expert_b, const int* __restrict__ tok_list,
    const float* __restrict__ w_list, const int* __restrict__ counts,
    float* __restrict__ out)
{
    const int bid = blockIdx.x;
    const int e   = bid / (TM_MAX * TILES_H);
    const int rem = bid % (TM_MAX * TILES_H);
    const int tm  = rem / TILES_H;
    const int th  = rem % TILES_H;     // th inner: consecutive bids share A-tile

    const int cnt = counts[e];
    if (tm * TM >= cnt) return;
    const int valid = cnt - tm * TM;
    const int hbase = th * TH;

    __shared__ __align__(16) short A_s[2][BUFSZ];   // 2 x 16 KB
    __shared__ __align__(16) short B_s[2][BUFSZ];   // 2 x 16 KB
    __shared__ int   tok_s[TM];
    __shared__ float wgt_s[TM];

    const int tid = threadIdx.x;
    if (tid < TM) {
        bool v = tid < valid;
        int src = e * REGION + tm * TM + tid;
        tok_s[tid] = v ? tok_list[src] : 0;
        wgt_s[tid] = v ? w_list[src] : 0.f;
    }
    __syncthreads();

    const int lane = tid & 63;
    const int wv = tid >> 6;

    // staging: wave wv owns 1KB chunks c = wv*4+j of each 16KB tile.
    // chunk c covers rows 8c..8c+7; lane l -> row c*8+(l>>3), slot l&7.
    // source slot XOR-swizzled (involution), LDS dest linear.
    const char* asrc[4];
    const char* bsrc[4];
    int dst_off[4];                    // shorts, wave-uniform (+lane*16B by HW)
#pragma unroll
    for (int j = 0; j < 4; ++j) {
        int c = wv * 4 + j;
        int r = c * 8 + (lane >> 3);
        int c16 = (lane & 7) ^ (r & 7);
        asrc[j] = (const char*)(xb + (size_t)tok_s[r] * D_IN) + c16 * 16;
        bsrc[j] = (const char*)(wb + ((size_t)e * H_OUT + hbase + r) * D_IN) + c16 * 16;
        dst_off[j] = c * 512;
    }

    const int rr = lane & 15, kg = lane >> 4;
    const int wr = wv >> 1, wc = wv & 1;

    // fragment LDS offsets (shorts), swizzled to match staging involution
    int aoff[4][2], boff[4][2];
#pragma unroll
    for (int mi = 0; mi < 4; ++mi)
#pragma unroll
        for (int k2 = 0; k2 < 2; ++k2) {
            int row = wr * 64 + mi * 16 + rr;
            int c16 = (k2 * 4 + kg) ^ (row & 7);
            aoff[mi][k2] = row * 64 + c16 * 8;
            int rowb = wc * 64 + mi * 16 + rr;
            int c16b = (k2 * 4 + kg) ^ (rowb & 7);
            boff[mi][k2] = rowb * 64 + c16b * 8;
        }

    f32x4 acc[4][4] = {};

    // prologue: stage K-tile 0 into buf 0
#pragma unroll
    for (int j = 0; j < 4; ++j) {
        gload16(asrc[j], (short*)A_s[0] + dst_off[j]); asrc[j] += BK * 2;
        gload16(bsrc[j], (short*)B_s[0] + dst_off[j]); bsrc[j] += BK * 2;
    }
    __syncthreads();

    for (int kk = 0; kk < NKT; ++kk) {
        const short* Ac = A_s[kk & 1];
        const short* Bc = B_s[kk & 1];
        short* An = (short*)A_s[(kk + 1) & 1];
        short* Bn = (short*)B_s[(kk + 1) & 1];

        // stage next K-tile FIRST (loads fly under this tile's compute)
        if (kk + 1 < NKT) {
#pragma unroll
            for (int j = 0; j < 4; ++j) {
                gload16(asrc[j], An + dst_off[j]); asrc[j] += BK * 2;
                gload16(bsrc[j], Bn + dst_off[j]); bsrc[j] += BK * 2;
            }
        }

#pragma unroll
        for (int k2 = 0; k2 < 2; ++k2) {
            bf16x8 af[4], bv[4];
#pragma unroll
            for (int mi = 0; mi < 4; ++mi) af[mi] = *(const bf16x8*)&Ac[aoff[mi][k2]];
#pragma unroll
            for (int ni = 0; ni < 4; ++ni) bv[ni] = *(const bf16x8*)&Bc[boff[ni][k2]];
#pragma unroll
            for (int mi = 0; mi < 4; ++mi)
#pragma unroll
                for (int ni = 0; ni < 4; ++ni)
                    acc[mi][ni] = __builtin_amdgcn_mfma_f32_16x16x32_bf16(
                        af[mi], bv[ni], acc[mi][ni], 0, 0, 0);
        }

        // one barrier per K-tile: drains stage loads (full-tile cover) and
        // protects next iteration's buffer swap.
        __syncthreads();
    }

    // epilogue: C/D layout col=lane&15, row=(lane>>4)*4+i
    const float* bias = expert_b + (size_t)e * H_OUT + hbase;
#pragma unroll
    for (int mi = 0; mi < 4; ++mi) {
#pragma unroll
        for (int ni = 0; ni < 4; ++ni) {
            int col = wc * 64 + ni * 16 + rr;
            float be = bias[col];
#pragma unroll
            for (int i = 0; i < 4; ++i) {
                int r = wr * 64 + mi * 16 + kg * 4 + i;
                if (r < valid) {
                    float val = wgt_s[r] * (acc[mi][ni][i] + be);
                    atomicAdd(&out[(size_t)tok_s[r] * H_OUT + hbase + col], val);
                }
            }
        }
    }
}

// ---------------------------------------------------------------------------
// Workspace layout (<= 162 MB):
//   0        topk_idx    64 KB
//   64K      topk_w      64 KB
//   128K     cursors     64 B
//   128K+256 ent_partial 8 KB
//   160K     tok_list    256 KB  (8 regions x 8192)
//   416K     w_list      256 KB
//   1M       xb  bf16    32 MB
//   34M      wb  bf16    128 MB
// ---------------------------------------------------------------------------
extern "C" void kernel_launch(void* const* d_in, const int* in_sizes, int n_in,
                              void* d_out, int out_size, void* d_ws, size_t ws_size,
                              hipStream_t stream) {
    const float* x        = (const float*)d_in[0];
    const float* gate_w   = (const float*)d_in[1];
    const float* gate_b   = (const float*)d_in[2];
    const float* expert_w = (const float*)d_in[3];
    const float* expert_b = (const float*)d_in[4];
    float* out = (float*)d_out;
    char* ws = (char*)d_ws;

    int*   topk_idx    = (int*)(ws);
    float* topk_w      = (float*)(ws + (64 << 10));
    int*   cursors     = (int*)(ws + (128 << 10));
    float* ent_partial = (float*)(ws + (128 << 10) + 256);
    int*   tok_list    = (int*)(ws + (160 << 10));
    float* w_list      = (float*)(ws + (416 << 10));
    short* xb          = (short*)(ws + (1ull << 20));
    short* wb          = (short*)(ws + (34ull << 20));

    hipMemsetAsync(cursors, 0, 64, stream);
    hipMemsetAsync(d_out, 0, (size_t)out_size * sizeof(float), stream);

    gate_kernel<<<N_TOK / 4, 256, 0, stream>>>(x, gate_w, gate_b, topk_idx,
                                               topk_w, ent_partial, xb);
    cvt_kernel<<<4096, 256, 0, stream>>>(expert_w, wb, (NEXP * H_OUT * D_IN) / 8);
    scatter_kernel<<<N_TOK / 256, 256, 0, stream>>>(topk_idx, topk_w, cursors,
                                                    tok_list, w_list);
    finalize_kernel<<<1, 256, 0, stream>>>(cursors, ent_partial,
                                           out + (size_t)N_TOK * H_OUT);
    moe_gemm<<<NEXP * TM_MAX * TILES_H, 256, 0, stream>>>(
        xb, wb, expert_b, tok_list, w_list, cursors, out);
}

// Round 5
// 719.720 us; speedup vs baseline: 2.5102x; 1.1476x over previous
//
#include <hip/hip_runtime.h>

// Problem constants
constexpr int N_TOK = 8192;      // B*S
constexpr int D_IN  = 2048;
constexpr int H_OUT = 4096;
constexpr int NEXP  = 8;
constexpr float ENT_W = 0.1f;
constexpr float MAX_USAGE = 0.3f;

// GEMM tiling
constexpr int TM = 128;               // token-tile
constexpr int TH = 128;               // H-tile
constexpr int BK = 64;                // K-step (128 bytes bf16 per row)
constexpr int NKT = D_IN / BK;        // 32 K-tiles
constexpr int TILES_H = H_OUT / TH;   // 32
constexpr int TM_MAX  = N_TOK / TM;   // 64 worst-case token tiles per expert
constexpr int REGION  = 8192;         // per-expert list capacity
constexpr int BUFSZ   = TM * BK;      // shorts per LDS buffer (8192)

typedef __attribute__((ext_vector_type(8))) short bf16x8;
typedef __attribute__((ext_vector_type(4))) float f32x4;

__device__ __forceinline__ short f2bf(float f) {
    unsigned u = __float_as_uint(f);
    u += 0x7FFF + ((u >> 16) & 1);   // RNE
    return (short)(u >> 16);
}

__device__ __forceinline__ void gload16(const void* g, void* l) {
    __builtin_amdgcn_global_load_lds(
        (const __attribute__((address_space(1))) unsigned int*)g,
        (__attribute__((address_space(3))) unsigned int*)l, 16, 0, 0);
}

// ---------------------------------------------------------------------------
// fp32 -> bf16 bulk convert (expert_w only; x is fused into gate)
// ---------------------------------------------------------------------------
__global__ __launch_bounds__(256) void cvt_kernel(
    const float* __restrict__ in, short* __restrict__ out, int n8)
{
    int stride = gridDim.x * 256;
    for (int i = blockIdx.x * 256 + threadIdx.x; i < n8; i += stride) {
        const float4* p = (const float4*)in + (size_t)i * 2;
        float4 a = p[0], b = p[1];
        bf16x8 v;
        v[0] = f2bf(a.x); v[1] = f2bf(a.y); v[2] = f2bf(a.z); v[3] = f2bf(a.w);
        v[4] = f2bf(b.x); v[5] = f2bf(b.y); v[6] = f2bf(b.z); v[7] = f2bf(b.w);
        *(bf16x8*)(out + (size_t)i * 8) = v;
    }
}

// ---------------------------------------------------------------------------
// Kernel 1: gating. One wave per token; fuses x -> bf16 conversion.
// ---------------------------------------------------------------------------
__global__ __launch_bounds__(256) void gate_kernel(
    const float* __restrict__ x, const float* __restrict__ gate_w,
    const float* __restrict__ gate_b, int* __restrict__ topk_idx,
    float* __restrict__ topk_w, float* __restrict__ ent_partial,
    short* __restrict__ xb)
{
    __shared__ float ent_s[4];
    const int wv = threadIdx.x >> 6;
    const int lane = threadIdx.x & 63;
    const int t = blockIdx.x * 4 + wv;

    float acc[NEXP];
#pragma unroll
    for (int e = 0; e < NEXP; ++e) acc[e] = 0.f;

    const float4* xr = (const float4*)(x + (size_t)t * D_IN);
    short* xbr = xb + (size_t)t * D_IN;
#pragma unroll
    for (int i = 0; i < D_IN / 256; ++i) {           // 8 iters
        float4 xv = xr[lane + i * 64];
        short4 s4;
        s4.x = f2bf(xv.x); s4.y = f2bf(xv.y); s4.z = f2bf(xv.z); s4.w = f2bf(xv.w);
        *(short4*)(xbr + i * 256 + lane * 4) = s4;
#pragma unroll
        for (int e = 0; e < NEXP; ++e) {
            float4 gv = ((const float4*)(gate_w + e * D_IN))[lane + i * 64];
            acc[e] += xv.x * gv.x + xv.y * gv.y + xv.z * gv.z + xv.w * gv.w;
        }
    }
#pragma unroll
    for (int e = 0; e < NEXP; ++e)
#pragma unroll
        for (int m = 32; m >= 1; m >>= 1) acc[e] += __shfl_xor(acc[e], m, 64);

    if (lane == 0) {
        float lg[NEXP], p[NEXP];
        float mx = -1e30f;
#pragma unroll
        for (int e = 0; e < NEXP; ++e) { lg[e] = acc[e] + gate_b[e]; mx = fmaxf(mx, lg[e]); }
        float s = 0.f;
#pragma unroll
        for (int e = 0; e < NEXP; ++e) { p[e] = expf(lg[e] - mx); s += p[e]; }
        float inv = 1.f / s;
        float ent = 0.f;
#pragma unroll
        for (int e = 0; e < NEXP; ++e) { p[e] *= inv; ent -= p[e] * logf(p[e] + 1e-10f); }
        int e1 = 0; float b1 = p[0];
#pragma unroll
        for (int e = 1; e < NEXP; ++e) if (p[e] > b1) { b1 = p[e]; e1 = e; }
        int e2 = (e1 == 0) ? 1 : 0; float b2 = p[e2];
#pragma unroll
        for (int e = 0; e < NEXP; ++e)
            if (e != e1 && e != ((e1 == 0) ? 1 : 0) && p[e] > b2) { b2 = p[e]; e2 = e; }
        topk_idx[2 * t]     = e1;  topk_idx[2 * t + 1] = e2;
        topk_w[2 * t]       = b1;  topk_w[2 * t + 1]   = b2;
        ent_s[wv] = ent;
    }
    __syncthreads();
    if (threadIdx.x == 0)
        ent_partial[blockIdx.x] = ent_s[0] + ent_s[1] + ent_s[2] + ent_s[3];
}

// ---------------------------------------------------------------------------
// Kernel 2: scatter. LDS-binned, fixed per-expert regions.
// ---------------------------------------------------------------------------
__global__ __launch_bounds__(256) void scatter_kernel(
    const int* __restrict__ topk_idx, const float* __restrict__ topk_w,
    int* __restrict__ cursors, int* __restrict__ tok_list,
    float* __restrict__ w_list)
{
    __shared__ int lcnt[NEXP], lbase[NEXP];
    const int tid = threadIdx.x;
    const int t = blockIdx.x * 256 + tid;
    if (tid < NEXP) lcnt[tid] = 0;
    __syncthreads();
    int e0 = topk_idx[2 * t], e1 = topk_idx[2 * t + 1];
    float w0 = topk_w[2 * t], w1 = topk_w[2 * t + 1];
    int p0 = atomicAdd(&lcnt[e0], 1);
    int p1 = atomicAdd(&lcnt[e1], 1);
    __syncthreads();
    if (tid < NEXP) lbase[tid] = atomicAdd(&cursors[tid], lcnt[tid]);
    __syncthreads();
    int d0 = e0 * REGION + lbase[e0] + p0;
    int d1 = e1 * REGION + lbase[e1] + p1;
    tok_list[d0] = t;  w_list[d0] = w0;
    tok_list[d1] = t;  w_list[d1] = w1;
}

// ---------------------------------------------------------------------------
// Kernel 3: finalize — entropy reduce + overuse penalty (counts = cursors).
// ---------------------------------------------------------------------------
__global__ __launch_bounds__(256) void finalize_kernel(
    const int* __restrict__ counts, const float* __restrict__ ent_partial,
    float* __restrict__ loss_out)
{
    __shared__ float red[256];
    float s = 0.f;
    for (int i = threadIdx.x; i < N_TOK / 4; i += 256) s += ent_partial[i];
    red[threadIdx.x] = s;
    __syncthreads();
    for (int st = 128; st > 0; st >>= 1) {
        if (threadIdx.x < st) red[threadIdx.x] += red[threadIdx.x + st];
        __syncthreads();
    }
    if (threadIdx.x == 0) {
        float loss = ENT_W * red[0] / (float)N_TOK;
        for (int e = 0; e < NEXP; ++e) {
            float r = (float)counts[e] / (float)N_TOK - MAX_USAGE;
            if (r > 0.f) loss += r;
        }
        loss_out[0] = loss;
    }
}

// ---------------------------------------------------------------------------
// Kernel 4: grouped GEMM — 128x128/BK=64/4-wave, double-buffered LDS with
// DEPTH-2 counted-vmcnt pipeline (register-consume frees the buffer):
//   tile t: ds_read all of buf[t&1] -> regs; lgkmcnt(0); s_barrier
//           issue tile t+2 gloads -> buf[t&1]; MFMA (reg-only, covers loads)
//           vmcnt(8) certifies tile t+1 (issued one full tile earlier); s_barrier
// No vmcnt(0) in the main loop. Swizzle scheme unchanged (0 conflicts, r2).
// ---------------------------------------------------------------------------
__global__ __launch_bounds__(256) void moe_gemm(
    const short* __restrict__ xb, const short* __restrict__ wb,
    const float* __restrict__ expert_b, const int* __restrict__ tok_list,
    const float* __restrict__ w_list, const int* __restrict__ counts,
    float* __restrict__ out)
{
    const int bid = blockIdx.x;
    const int e   = bid / (TM_MAX * TILES_H);
    const int rem = bid % (TM_MAX * TILES_H);
    const int tm  = rem / TILES_H;
    const int th  = rem % TILES_H;     // th inner: consecutive bids share A-tile

    const int cnt = counts[e];
    if (tm * TM >= cnt) return;
    const int valid = cnt - tm * TM;
    const int hbase = th * TH;

    __shared__ __align__(16) short A_s[2][BUFSZ];   // 2 x 16 KB
    __shared__ __align__(16) short B_s[2][BUFSZ];   // 2 x 16 KB
    __shared__ int   tok_s[TM];
    __shared__ float wgt_s[TM];

    const int tid = threadIdx.x;
    if (tid < TM) {
        bool v = tid < valid;
        int src = e * REGION + tm * TM + tid;
        tok_s[tid] = v ? tok_list[src] : 0;
        wgt_s[tid] = v ? w_list[src] : 0.f;
    }
    __syncthreads();

    const int lane = tid & 63;
    const int wv = tid >> 6;

    // staging: wave wv owns 1KB chunks c = wv*4+j of each 16KB tile.
    // chunk c covers rows 8c..8c+7; lane l -> row c*8+(l>>3), slot l&7.
    // source slot XOR-swizzled (involution), LDS dest linear.
    const char* asrc[4];
    const char* bsrc[4];
    int dst_off[4];                    // shorts, wave-uniform (+lane*16B by HW)
#pragma unroll
    for (int j = 0; j < 4; ++j) {
        int c = wv * 4 + j;
        int r = c * 8 + (lane >> 3);
        int c16 = (lane & 7) ^ (r & 7);
        asrc[j] = (const char*)(xb + (size_t)tok_s[r] * D_IN) + c16 * 16;
        bsrc[j] = (const char*)(wb + ((size_t)e * H_OUT + hbase + r) * D_IN) + c16 * 16;
        dst_off[j] = c * 512;
    }

    const int rr = lane & 15, kg = lane >> 4;
    const int wr = wv >> 1, wc = wv & 1;

    // fragment LDS offsets (shorts), swizzled to match staging involution
    int aoff[4][2], boff[4][2];
#pragma unroll
    for (int mi = 0; mi < 4; ++mi)
#pragma unroll
        for (int k2 = 0; k2 < 2; ++k2) {
            int row = wr * 64 + mi * 16 + rr;
            int c16 = (k2 * 4 + kg) ^ (row & 7);
            aoff[mi][k2] = row * 64 + c16 * 8;
            int rowb = wc * 64 + mi * 16 + rr;
            int c16b = (k2 * 4 + kg) ^ (rowb & 7);
            boff[mi][k2] = rowb * 64 + c16b * 8;
        }

    f32x4 acc[4][4] = {};

    // prologue: stage K-tiles 0 (buf0) and 1 (buf1); certify tile 0 only.
#pragma unroll
    for (int j = 0; j < 4; ++j) {
        gload16(asrc[j], (short*)A_s[0] + dst_off[j]); asrc[j] += BK * 2;
        gload16(bsrc[j], (short*)B_s[0] + dst_off[j]); bsrc[j] += BK * 2;
    }
#pragma unroll
    for (int j = 0; j < 4; ++j) {
        gload16(asrc[j], (short*)A_s[1] + dst_off[j]); asrc[j] += BK * 2;
        gload16(bsrc[j], (short*)B_s[1] + dst_off[j]); bsrc[j] += BK * 2;
    }
    asm volatile("s_waitcnt vmcnt(8)" ::: "memory");   // tile 0 landed
    __builtin_amdgcn_sched_barrier(0);
    __builtin_amdgcn_s_barrier();

    for (int kt = 0; kt < NKT; ++kt) {
        const short* Ac = A_s[kt & 1];
        const short* Bc = B_s[kt & 1];
        short* An = (short*)A_s[kt & 1];   // freed below; receives tile kt+2
        short* Bn = (short*)B_s[kt & 1];

        // consume current tile entirely into registers
        bf16x8 af[4][2], bv[4][2];
#pragma unroll
        for (int k2 = 0; k2 < 2; ++k2) {
#pragma unroll
            for (int mi = 0; mi < 4; ++mi) af[mi][k2] = *(const bf16x8*)&Ac[aoff[mi][k2]];
#pragma unroll
            for (int ni = 0; ni < 4; ++ni) bv[ni][k2] = *(const bf16x8*)&Bc[boff[ni][k2]];
        }
        asm volatile("s_waitcnt lgkmcnt(0)" ::: "memory");
        __builtin_amdgcn_sched_barrier(0);
        __builtin_amdgcn_s_barrier();          // all waves done reading buf[kt&1]

        // stage tile kt+2 into the buffer just freed (loads fly under MFMA)
        if (kt + 2 < NKT) {
#pragma unroll
            for (int j = 0; j < 4; ++j) {
                gload16(asrc[j], An + dst_off[j]); asrc[j] += BK * 2;
                gload16(bsrc[j], Bn + dst_off[j]); bsrc[j] += BK * 2;
            }
        }

        __builtin_amdgcn_s_setprio(1);
#pragma unroll
        for (int k2 = 0; k2 < 2; ++k2)
#pragma unroll
            for (int mi = 0; mi < 4; ++mi)
#pragma unroll
                for (int ni = 0; ni < 4; ++ni)
                    acc[mi][ni] = __builtin_amdgcn_mfma_f32_16x16x32_bf16(
                        af[mi][k2], bv[ni][k2], acc[mi][ni], 0, 0, 0);
        __builtin_amdgcn_s_setprio(0);

        // certify tile kt+1 (its 8 loads were issued one full tile ago);
        // never drain to 0 while deeper prefetch is in flight.
        if (kt + 2 < NKT) {
            asm volatile("s_waitcnt vmcnt(8)" ::: "memory");
        } else if (kt + 1 < NKT) {
            asm volatile("s_waitcnt vmcnt(0)" ::: "memory");
        }
        __builtin_amdgcn_sched_barrier(0);
        __builtin_amdgcn_s_barrier();          // buf[(kt+1)&1] valid for all
    }

    // epilogue: C/D layout col=lane&15, row=(lane>>4)*4+i
    const float* bias = expert_b + (size_t)e * H_OUT + hbase;
#pragma unroll
    for (int mi = 0; mi < 4; ++mi) {
#pragma unroll
        for (int ni = 0; ni < 4; ++ni) {
            int col = wc * 64 + ni * 16 + rr;
            float be = bias[col];
#pragma unroll
            for (int i = 0; i < 4; ++i) {
                int r = wr * 64 + mi * 16 + kg * 4 + i;
                if (r < valid) {
                    float val = wgt_s[r] * (acc[mi][ni][i] + be);
                    atomicAdd(&out[(size_t)tok_s[r] * H_OUT + hbase + col], val);
                }
            }
        }
    }
}

// ---------------------------------------------------------------------------
// Workspace layout (<= 162 MB):
//   0        topk_idx    64 KB
//   64K      topk_w      64 KB
//   128K     cursors     64 B
//   128K+256 ent_partial 8 KB
//   160K     tok_list    256 KB  (8 regions x 8192)
//   416K     w_list      256 KB
//   1M       xb  bf16    32 MB
//   34M      wb  bf16    128 MB
// ---------------------------------------------------------------------------
extern "C" void kernel_launch(void* const* d_in, const int* in_sizes, int n_in,
                              void* d_out, int out_size, void* d_ws, size_t ws_size,
                              hipStream_t stream) {
    const float* x        = (const float*)d_in[0];
    const float* gate_w   = (const float*)d_in[1];
    const float* gate_b   = (const float*)d_in[2];
    const float* expert_w = (const float*)d_in[3];
    const float* expert_b = (const float*)d_in[4];
    float* out = (float*)d_out;
    char* ws = (char*)d_ws;

    int*   topk_idx    = (int*)(ws);
    float* topk_w      = (float*)(ws + (64 << 10));
    int*   cursors     = (int*)(ws + (128 << 10));
    float* ent_partial = (float*)(ws + (128 << 10) + 256);
    int*   tok_list    = (int*)(ws + (160 << 10));
    float* w_list      = (float*)(ws + (416 << 10));
    short* xb          = (short*)(ws + (1ull << 20));
    short* wb          = (short*)(ws + (34ull << 20));

    hipMemsetAsync(cursors, 0, 64, stream);
    hipMemsetAsync(d_out, 0, (size_t)out_size * sizeof(float), stream);

    gate_kernel<<<N_TOK / 4, 256, 0, stream>>>(x, gate_w, gate_b, topk_idx,
                                               topk_w, ent_partial, xb);
    cvt_kernel<<<4096, 256, 0, stream>>>(expert_w, wb, (NEXP * H_OUT * D_IN) / 8);
    scatter_kernel<<<N_TOK / 256, 256, 0, stream>>>(topk_idx, topk_w, cursors,
                                                    tok_list, w_list);
    finalize_kernel<<<1, 256, 0, stream>>>(cursors, ent_partial,
                                           out + (size_t)N_TOK * H_OUT);
    moe_gemm<<<NEXP * TM_MAX * TILES_H, 256, 0, stream>>>(
        xb, wb, expert_b, tok_list, w_list, cursors, out);
}